// Round 6
// baseline (493.414 us; speedup 1.0000x reference)
//
#include <hip/hip_runtime.h>

#define NN 100000
#define NE 1600000
#define DD 128

typedef short short8 __attribute__((ext_vector_type(8)));
typedef float f32x4 __attribute__((ext_vector_type(4)));

// ---------------- bf16 helpers ----------------

__device__ __forceinline__ unsigned short f2bf(float f) {
    union { float f; unsigned u; } v; v.f = f;
    unsigned r = v.u + 0x7FFF + ((v.u >> 16) & 1);  // round-to-nearest-even
    return (unsigned short)(r >> 16);
}
__device__ __forceinline__ float bf2f(unsigned short b) {
    union { unsigned u; float f; } v; v.u = (unsigned)b << 16;
    return v.f;
}

// ---------------- CSR construction ----------------

__global__ __launch_bounds__(256) void k_count(const int* __restrict__ dstA,
                                               int* __restrict__ cnt, int E) {
    int i = blockIdx.x * 256 + threadIdx.x;
    if (i < E) atomicAdd(&cnt[dstA[i]], 1);
}

__global__ __launch_bounds__(256) void k_dinv(const int* __restrict__ rowp,
                                              float* __restrict__ dinv, int N) {
    int n = blockIdx.x * 256 + threadIdx.x;
    if (n < N) dinv[n] = rsqrtf(2.0f + (float)rowp[n + 1]);  // self-loop weight 2.0
}

__global__ __launch_bounds__(256) void k_scan1(int* __restrict__ rowp,
                                               int* __restrict__ bsum, int N) {
    __shared__ int sm[256];
    int tid = threadIdx.x;
    int i = blockIdx.x * 256 + tid;
    int v = (i < N) ? rowp[1 + i] : 0;
    sm[tid] = v;
    #pragma unroll
    for (int off = 1; off < 256; off <<= 1) {
        __syncthreads();
        int t = (tid >= off) ? sm[tid - off] : 0;
        __syncthreads();
        sm[tid] += t;
    }
    if (i < N) rowp[1 + i] = sm[tid];
    if (tid == 255) bsum[blockIdx.x] = sm[255];
}

__global__ __launch_bounds__(512) void k_scan2(int* __restrict__ bsum, int nb) {
    __shared__ int sm[512];
    int tid = threadIdx.x;
    sm[tid] = (tid < nb) ? bsum[tid] : 0;
    #pragma unroll
    for (int off = 1; off < 512; off <<= 1) {
        __syncthreads();
        int t = (tid >= off) ? sm[tid - off] : 0;
        __syncthreads();
        sm[tid] += t;
    }
    if (tid < nb) bsum[tid] = sm[tid];
}

// finalize rowp; emit per-bucket (128 nodes) start cursors for the partition pass
__global__ __launch_bounds__(256) void k_scan3(int* __restrict__ rowp,
                                               const int* __restrict__ bsum,
                                               int* __restrict__ bcur, int N) {
    int tid = threadIdx.x;
    int i = blockIdx.x * 256 + tid;
    if (i >= N) return;
    int add = (blockIdx.x > 0) ? bsum[blockIdx.x - 1] : 0;
    int fin = rowp[1 + i] + add;
    rowp[1 + i] = fin;
    if (i == 0) bcur[0] = 0;
    if (((i + 1) & 127) == 0 && (i + 1) < N) bcur[(i + 1) >> 7] = fin;
}

// phase 1: chunked bucketing with block-aggregated atomics.
__global__ __launch_bounds__(256) void k_part(const int* __restrict__ srcA,
                                              const int* __restrict__ dstA,
                                              int* __restrict__ bcur,
                                              uint2* __restrict__ tmp, int E, int NBk) {
    __shared__ int cur[1024];
    int tid = threadIdx.x;
    int chunk = (E + gridDim.x - 1) / gridDim.x;
    int e0 = blockIdx.x * chunk;
    int e1 = e0 + chunk; e1 = e1 < E ? e1 : E;
    if (e0 >= e1) return;

    for (int b = tid; b < NBk; b += 256) cur[b] = 0;
    __syncthreads();
    for (int i = e0 + tid; i < e1; i += 256)
        atomicAdd(&cur[dstA[i] >> 7], 1);
    __syncthreads();
    for (int b = tid; b < NBk; b += 256) {
        int c = cur[b];
        cur[b] = (c > 0) ? atomicAdd(&bcur[b], c) : 0;
    }
    __syncthreads();
    for (int i = e0 + tid; i < e1; i += 256) {
        int s = srcA[i], d = dstA[i];
        int slot = atomicAdd(&cur[d >> 7], 1);
        uint2 p; p.x = (unsigned)s; p.y = (unsigned)d;
        tmp[slot] = p;
    }
}

// phase 2: exact CSR placement within each bucket via LDS cursors
__global__ __launch_bounds__(256) void k_place(const uint2* __restrict__ tmp,
                                               const int* __restrict__ rowp,
                                               int* __restrict__ col, int N) {
    __shared__ int lcur[128];
    int b = blockIdx.x;
    int n0 = b << 7;
    int tid = threadIdx.x;
    int nEnd = n0 + 128; nEnd = nEnd < N ? nEnd : N;
    int base = rowp[n0];
    int cnt = rowp[nEnd] - base;
    if (tid < 128) {
        int node = n0 + tid;
        lcur[tid] = (node < N) ? (rowp[node] - base) : 0;
    }
    __syncthreads();
    for (int i = tid; i < cnt; i += 256) {
        uint2 p = tmp[base + i];
        int j = (int)p.y - n0;
        int slot = atomicAdd(&lcur[j], 1);
        col[base + slot] = (int)p.x;
    }
}

// ---------------- W preparation: fp32 W[k][n] -> global swizzled bf16 hi/lo ----------------
// layout (bytes, per layer, 64KB): [0,32K) hi, [32K,64K) lo; within each:
// byte addr = (n*256 + 2k) ^ ((n&7)<<4)
__global__ __launch_bounds__(256) void k_prep(const float* __restrict__ W,
                                              unsigned short* __restrict__ wt) {
    int tid = threadIdx.x;
    const float* Wsrc = W;
    char* hiB = (char*)wt;
    char* loB = (char*)wt + 32768;
    for (int idx = tid; idx < 128 * 128; idx += 256) {
        int k = idx >> 7, n = idx & 127;
        float w = Wsrc[idx];
        unsigned u = __float_as_uint(w);
        unsigned short hi = (unsigned short)(u >> 16);            // truncate
        float lof = w - __uint_as_float((unsigned)hi << 16);      // exact residual
        unsigned short lo = f2bf(lof);                            // rte
        int ba = (n * 256 + 2 * k) ^ ((n & 7) << 4);
        *(unsigned short*)(hiB + ba) = hi;
        *(unsigned short*)(loB + ba) = lo;
    }
}

// ---------------- dense transform: Hb = bf16(F @ W), MFMA ----------------
// h = a@Whi + a@Wlo with a = bf16(F) (rte); W hi/lo from pre-swizzled global.
// block = 512 (8 waves); wave w computes rows [blk*128 + w*16, +16) x 128 cols.

__global__ __launch_bounds__(512) void k_gemm(const float* __restrict__ F,
                                              const unsigned short* __restrict__ wt,
                                              unsigned short* __restrict__ Hb, int N) {
    __shared__ char Wl[65536];  // [0,32K) hi, [32K,64K) lo, swizzled
    int tid = threadIdx.x;

    // stage: flat 64KB copy (layout already transposed+swizzled)
    {
        const uint4* src = reinterpret_cast<const uint4*>(wt);
        uint4* dst = reinterpret_cast<uint4*>(Wl);
        #pragma unroll
        for (int i = 0; i < 8; ++i) dst[tid + 512 * i] = src[tid + 512 * i];
    }
    __syncthreads();

    int wv = tid >> 6;       // wave 0..7
    int l  = tid & 63;
    int nn = l & 15;         // A row / B col / D col within tile
    int g  = l >> 4;         // k-subgroup (and D row group)
    int r0w = blockIdx.x * 128 + wv * 16;

    int row = r0w + nn;
    row = row < N ? row : N - 1;  // clamp (stores guarded)
    const float4* Fr = reinterpret_cast<const float4*>(&F[(size_t)row * DD]);

    f32x4 acc[8];
    #pragma unroll
    for (int nt = 0; nt < 8; ++nt) acc[nt] = (f32x4){0.f, 0.f, 0.f, 0.f};

    #pragma unroll
    for (int ks = 0; ks < 4; ++ks) {
        float4 f0 = Fr[ks * 8 + g * 2];
        float4 f1 = Fr[ks * 8 + g * 2 + 1];
        short8 a;
        a[0] = (short)f2bf(f0.x); a[1] = (short)f2bf(f0.y);
        a[2] = (short)f2bf(f0.z); a[3] = (short)f2bf(f0.w);
        a[4] = (short)f2bf(f1.x); a[5] = (short)f2bf(f1.y);
        a[6] = (short)f2bf(f1.z); a[7] = (short)f2bf(f1.w);
        #pragma unroll
        for (int nt = 0; nt < 8; ++nt) {
            int ba = ((nt * 16 + nn) * 256 + ks * 64 + g * 16) ^ ((nn & 7) << 4);
            short8 bhi = *(const short8*)(Wl + ba);
            short8 blo = *(const short8*)(Wl + 32768 + ba);
            acc[nt] = __builtin_amdgcn_mfma_f32_16x16x32_bf16(a, blo, acc[nt], 0, 0, 0);
            acc[nt] = __builtin_amdgcn_mfma_f32_16x16x32_bf16(a, bhi, acc[nt], 0, 0, 0);
        }
    }

    // D layout: col = lane&15 (nn), row = 4*(lane>>4) + j
    #pragma unroll
    for (int nt = 0; nt < 8; ++nt) {
        #pragma unroll
        for (int j = 0; j < 4; ++j) {
            int r = r0w + 4 * g + j;
            if (r < N) Hb[(size_t)r * DD + nt * 16 + nn] = f2bf(acc[nt][j]);
        }
    }
}

// ---------------- aggregation ----------------
// OUT[n] = dinv[n] * sum_e dinv[col[e]]*Hb[col[e]] + 2*dinv[n]^2*Hb[n] + b + F[n] (+X[n])

__global__ __launch_bounds__(256) void k_agg(const unsigned short* __restrict__ Hb,
                                             const int* __restrict__ rowp,
                                             const int* __restrict__ col,
                                             const float* __restrict__ dinv,
                                             const float* __restrict__ bias,
                                             const float* __restrict__ F,
                                             const float* __restrict__ X,
                                             float* __restrict__ OUT, int N, int addX) {
    int lane = threadIdx.x & 63;
    int n = (blockIdx.x << 2) + (threadIdx.x >> 6);
    if (n >= N) return;
    int c = lane << 1;
    size_t base = (size_t)n * DD + c;

    float di = dinv[n];
    unsigned hv = *reinterpret_cast<const unsigned*>(&Hb[base]);
    float s2 = 2.f * di * di;
    float sx = s2 * bf2f((unsigned short)(hv & 0xffff));
    float sy = s2 * bf2f((unsigned short)(hv >> 16));
    float ax = 0.f, ay = 0.f;  // edge accumulation (di applied at end)

    int e = rowp[n], e1 = rowp[n + 1];
    for (; e + 8 <= e1; e += 8) {
        int s[8];
        float w[8];
        unsigned gg[8];
        #pragma unroll
        for (int j = 0; j < 8; ++j) s[j] = col[e + j];
        #pragma unroll
        for (int j = 0; j < 8; ++j) w[j] = dinv[s[j]];
        #pragma unroll
        for (int j = 0; j < 8; ++j)
            gg[j] = *reinterpret_cast<const unsigned*>(&Hb[(size_t)s[j] * DD + c]);
        #pragma unroll
        for (int j = 0; j < 8; ++j) {
            ax += w[j] * bf2f((unsigned short)(gg[j] & 0xffff));
            ay += w[j] * bf2f((unsigned short)(gg[j] >> 16));
        }
    }
    for (; e + 2 <= e1; e += 2) {
        int s0 = col[e], s1 = col[e + 1];
        float w0 = dinv[s0], w1 = dinv[s1];
        unsigned g0 = *reinterpret_cast<const unsigned*>(&Hb[(size_t)s0 * DD + c]);
        unsigned g1 = *reinterpret_cast<const unsigned*>(&Hb[(size_t)s1 * DD + c]);
        ax += w0 * bf2f((unsigned short)(g0 & 0xffff)) + w1 * bf2f((unsigned short)(g1 & 0xffff));
        ay += w0 * bf2f((unsigned short)(g0 >> 16))    + w1 * bf2f((unsigned short)(g1 >> 16));
    }
    if (e < e1) {
        int s0 = col[e];
        float w0 = dinv[s0];
        unsigned g0 = *reinterpret_cast<const unsigned*>(&Hb[(size_t)s0 * DD + c]);
        ax += w0 * bf2f((unsigned short)(g0 & 0xffff));
        ay += w0 * bf2f((unsigned short)(g0 >> 16));
    }

    float2 bv = *reinterpret_cast<const float2*>(&bias[c]);
    float2 fv = *reinterpret_cast<const float2*>(&F[base]);
    float ox = di * ax + sx + bv.x + fv.x;
    float oy = di * ay + sy + bv.y + fv.y;
    if (addX) {
        float2 xv = *reinterpret_cast<const float2*>(&X[base]);
        ox += xv.x;
        oy += xv.y;
    }
    float2 o;
    o.x = ox;
    o.y = oy;
    *reinterpret_cast<float2*>(&OUT[base]) = o;
}

// ---------------- launch ----------------

extern "C" void kernel_launch(void* const* d_in, const int* in_sizes, int n_in,
                              void* d_out, int out_size, void* d_ws, size_t ws_size,
                              hipStream_t stream) {
    const float* x  = (const float*)d_in[0];
    const int*   ei = (const int*)d_in[1];
    const float* W0 = (const float*)d_in[2];
    const float* b0 = (const float*)d_in[3];
    const float* W1 = (const float*)d_in[4];
    const float* b1 = (const float*)d_in[5];
    const float* W2 = (const float*)d_in[6];
    const float* b2 = (const float*)d_in[7];
    float* out = (float*)d_out;

    const int N = NN, E = NE;
    const int* srcA = ei;       // edge_index[0]
    const int* dstA = ei + E;   // edge_index[1]

    char* ws = (char*)d_ws;
    size_t off = 0;
    auto alloc = [&](size_t bytes) -> char* {
        char* p = ws + off;
        off += (bytes + 255) & ~size_t(255);
        return p;
    };
    int*   rowp   = (int*)  alloc((size_t)(N + 1) * sizeof(int));
    int*   bcur   = (int*)  alloc(1024 * sizeof(int));
    int*   bsum   = (int*)  alloc(512 * sizeof(int));
    float* dinv   = (float*)alloc((size_t)N * sizeof(float));
    int*   col    = (int*)  alloc((size_t)E * sizeof(int));
    uint2* tmp    = (uint2*)alloc((size_t)E * sizeof(uint2));
    unsigned short* h   = (unsigned short*)alloc((size_t)N * DD * sizeof(unsigned short));
    unsigned short* wt0 = (unsigned short*)alloc(65536);
    unsigned short* wt1 = (unsigned short*)alloc(65536);
    unsigned short* wt2 = (unsigned short*)alloc(65536);
    (void)ws_size; (void)in_sizes; (void)n_in; (void)out_size;

    hipMemsetAsync(rowp, 0, (size_t)(N + 1) * sizeof(int), stream);

    int gE = (E + 255) / 256;     // 6250
    int gN = (N + 255) / 256;     // 391
    int NB = (N + 127) / 128;     // 782 buckets
    k_count<<<gE, 256, 0, stream>>>(dstA, rowp + 1, E);
    k_prep <<<1, 256, 0, stream>>>(W0, wt0);
    k_prep <<<1, 256, 0, stream>>>(W1, wt1);
    k_prep <<<1, 256, 0, stream>>>(W2, wt2);
    k_dinv <<<gN, 256, 0, stream>>>(rowp, dinv, N);
    k_scan1<<<gN, 256, 0, stream>>>(rowp, bsum, N);
    k_scan2<<<1, 512, 0, stream>>>(bsum, gN);
    k_scan3<<<gN, 256, 0, stream>>>(rowp, bsum, bcur, N);
    k_part <<<256, 256, 0, stream>>>(srcA, dstA, bcur, tmp, E, NB);
    k_place<<<NB, 256, 0, stream>>>(tmp, rowp, col, N);

    int gG = (N + 127) / 128;  // 782
    int gA = (N + 3) / 4;      // 25000

    // layer 0: F = x -> out
    k_gemm<<<gG, 512, 0, stream>>>(x, wt0, h, N);
    k_agg <<<gA, 256, 0, stream>>>(h, rowp, col, dinv, b0, x, nullptr, out, N, 0);
    // layer 1: F = out -> out (in-place safe: each row read only by its own wave)
    k_gemm<<<gG, 512, 0, stream>>>(out, wt1, h, N);
    k_agg <<<gA, 256, 0, stream>>>(h, rowp, col, dinv, b1, out, nullptr, out, N, 0);
    // layer 2: F = out -> out, plus global residual x
    k_gemm<<<gG, 512, 0, stream>>>(out, wt2, h, N);
    k_agg <<<gA, 256, 0, stream>>>(h, rowp, col, dinv, b2, out, x, out, N, 1);
}

// Round 7
// 420.108 us; speedup vs baseline: 1.1745x; 1.1745x over previous
//
#include <hip/hip_runtime.h>

#define NN 100000
#define NE 1600000
#define DD 128

typedef short short8 __attribute__((ext_vector_type(8)));
typedef float f32x4 __attribute__((ext_vector_type(4)));

// ---------------- bf16 helpers ----------------

__device__ __forceinline__ unsigned short f2bf(float f) {
    union { float f; unsigned u; } v; v.f = f;
    unsigned r = v.u + 0x7FFF + ((v.u >> 16) & 1);  // round-to-nearest-even
    return (unsigned short)(r >> 16);
}
__device__ __forceinline__ float bf2f(unsigned short b) {
    union { unsigned u; float f; } v; v.u = (unsigned)b << 16;
    return v.f;
}

// ---------------- CSR construction ----------------

__global__ __launch_bounds__(256) void k_count(const int* __restrict__ dstA,
                                               int* __restrict__ cnt, int E) {
    int i = blockIdx.x * 256 + threadIdx.x;
    if (i < E) atomicAdd(&cnt[dstA[i]], 1);
}

__global__ __launch_bounds__(256) void k_dinv(const int* __restrict__ rowp,
                                              float* __restrict__ dinv, int N) {
    int n = blockIdx.x * 256 + threadIdx.x;
    if (n < N) dinv[n] = rsqrtf(2.0f + (float)rowp[n + 1]);  // self-loop weight 2.0
}

__global__ __launch_bounds__(256) void k_scan1(int* __restrict__ rowp,
                                               int* __restrict__ bsum, int N) {
    __shared__ int sm[256];
    int tid = threadIdx.x;
    int i = blockIdx.x * 256 + tid;
    int v = (i < N) ? rowp[1 + i] : 0;
    sm[tid] = v;
    #pragma unroll
    for (int off = 1; off < 256; off <<= 1) {
        __syncthreads();
        int t = (tid >= off) ? sm[tid - off] : 0;
        __syncthreads();
        sm[tid] += t;
    }
    if (i < N) rowp[1 + i] = sm[tid];
    if (tid == 255) bsum[blockIdx.x] = sm[255];
}

__global__ __launch_bounds__(512) void k_scan2(int* __restrict__ bsum, int nb) {
    __shared__ int sm[512];
    int tid = threadIdx.x;
    sm[tid] = (tid < nb) ? bsum[tid] : 0;
    #pragma unroll
    for (int off = 1; off < 512; off <<= 1) {
        __syncthreads();
        int t = (tid >= off) ? sm[tid - off] : 0;
        __syncthreads();
        sm[tid] += t;
    }
    if (tid < nb) bsum[tid] = sm[tid];
}

// finalize rowp; emit per-bucket (128 nodes) start cursors for the partition pass
__global__ __launch_bounds__(256) void k_scan3(int* __restrict__ rowp,
                                               const int* __restrict__ bsum,
                                               int* __restrict__ bcur, int N) {
    int tid = threadIdx.x;
    int i = blockIdx.x * 256 + tid;
    if (i >= N) return;
    int add = (blockIdx.x > 0) ? bsum[blockIdx.x - 1] : 0;
    int fin = rowp[1 + i] + add;
    rowp[1 + i] = fin;
    if (i == 0) bcur[0] = 0;
    if (((i + 1) & 127) == 0 && (i + 1) < N) bcur[(i + 1) >> 7] = fin;
}

// phase 1: chunked bucketing with block-aggregated atomics.
__global__ __launch_bounds__(256) void k_part(const int* __restrict__ srcA,
                                              const int* __restrict__ dstA,
                                              int* __restrict__ bcur,
                                              uint2* __restrict__ tmp, int E, int NBk) {
    __shared__ int cur[1024];
    int tid = threadIdx.x;
    int chunk = (E + gridDim.x - 1) / gridDim.x;
    int e0 = blockIdx.x * chunk;
    int e1 = e0 + chunk; e1 = e1 < E ? e1 : E;
    if (e0 >= e1) return;

    for (int b = tid; b < NBk; b += 256) cur[b] = 0;
    __syncthreads();
    for (int i = e0 + tid; i < e1; i += 256)
        atomicAdd(&cur[dstA[i] >> 7], 1);
    __syncthreads();
    for (int b = tid; b < NBk; b += 256) {
        int c = cur[b];
        cur[b] = (c > 0) ? atomicAdd(&bcur[b], c) : 0;
    }
    __syncthreads();
    for (int i = e0 + tid; i < e1; i += 256) {
        int s = srcA[i], d = dstA[i];
        int slot = atomicAdd(&cur[d >> 7], 1);
        uint2 p; p.x = (unsigned)s; p.y = (unsigned)d;
        tmp[slot] = p;
    }
}

// phase 2: exact CSR placement within each bucket via LDS cursors
__global__ __launch_bounds__(256) void k_place(const uint2* __restrict__ tmp,
                                               const int* __restrict__ rowp,
                                               int* __restrict__ col, int N) {
    __shared__ int lcur[128];
    int b = blockIdx.x;
    int n0 = b << 7;
    int tid = threadIdx.x;
    int nEnd = n0 + 128; nEnd = nEnd < N ? nEnd : N;
    int base = rowp[n0];
    int cnt = rowp[nEnd] - base;
    if (tid < 128) {
        int node = n0 + tid;
        lcur[tid] = (node < N) ? (rowp[node] - base) : 0;
    }
    __syncthreads();
    for (int i = tid; i < cnt; i += 256) {
        uint2 p = tmp[base + i];
        int j = (int)p.y - n0;
        int slot = atomicAdd(&lcur[j], 1);
        col[base + slot] = (int)p.x;
    }
}

// ---------------- W preparation: fp32 W[k][n] -> global swizzled bf16 hi/lo ----------------
// layout (bytes, per layer, 64KB): [0,32K) hi, [32K,64K) lo; within each:
// byte addr = (n*256 + 2k) ^ ((n&7)<<4).  grid = 64 blocks, 1 elem/thread.
__global__ __launch_bounds__(256) void k_prep(const float* __restrict__ W,
                                              unsigned short* __restrict__ wt) {
    int idx = blockIdx.x * 256 + threadIdx.x;   // 0..16383
    char* hiB = (char*)wt;
    char* loB = (char*)wt + 32768;
    int k = idx >> 7, n = idx & 127;
    float w = W[idx];
    unsigned u = __float_as_uint(w);
    unsigned short hi = (unsigned short)(u >> 16);            // truncate
    float lof = w - __uint_as_float((unsigned)hi << 16);      // exact residual
    unsigned short lo = f2bf(lof);                            // rte
    int ba = (n * 256 + 2 * k) ^ ((n & 7) << 4);
    *(unsigned short*)(hiB + ba) = hi;
    *(unsigned short*)(loB + ba) = lo;
}

// ---------------- dense transform: Hb = bf16(F @ W), MFMA ----------------
// h = a@Whi + a@Wlo with a = bf16(F) (rte); W hi/lo from pre-swizzled global.
// block = 512 (8 waves); wave w computes rows [blk*128 + w*16, +16) x 128 cols.
// Epilogue: reuse the (dead) W LDS as a [128][stride 272B] bf16 staging tile,
// then fully-coalesced uint4 global stores.

__global__ __launch_bounds__(512) void k_gemm(const float* __restrict__ F,
                                              const unsigned short* __restrict__ wt,
                                              unsigned short* __restrict__ Hb, int N) {
    __shared__ char Wl[65536];  // [0,32K) hi, [32K,64K) lo, swizzled; reused for epilogue
    int tid = threadIdx.x;

    // stage: flat 64KB copy (layout already transposed+swizzled)
    {
        const uint4* src = reinterpret_cast<const uint4*>(wt);
        uint4* dst = reinterpret_cast<uint4*>(Wl);
        #pragma unroll
        for (int i = 0; i < 8; ++i) dst[tid + 512 * i] = src[tid + 512 * i];
    }
    __syncthreads();

    int wv = tid >> 6;       // wave 0..7
    int l  = tid & 63;
    int nn = l & 15;         // A row / B col / D col within tile
    int g  = l >> 4;         // k-subgroup (and D row group)
    int r0w = blockIdx.x * 128 + wv * 16;

    int row = r0w + nn;
    row = row < N ? row : N - 1;  // clamp (stores guarded)
    const float4* Fr = reinterpret_cast<const float4*>(&F[(size_t)row * DD]);

    f32x4 acc[8];
    #pragma unroll
    for (int nt = 0; nt < 8; ++nt) acc[nt] = (f32x4){0.f, 0.f, 0.f, 0.f};

    #pragma unroll
    for (int ks = 0; ks < 4; ++ks) {
        float4 f0 = Fr[ks * 8 + g * 2];
        float4 f1 = Fr[ks * 8 + g * 2 + 1];
        short8 a;
        a[0] = (short)f2bf(f0.x); a[1] = (short)f2bf(f0.y);
        a[2] = (short)f2bf(f0.z); a[3] = (short)f2bf(f0.w);
        a[4] = (short)f2bf(f1.x); a[5] = (short)f2bf(f1.y);
        a[6] = (short)f2bf(f1.z); a[7] = (short)f2bf(f1.w);
        #pragma unroll
        for (int nt = 0; nt < 8; ++nt) {
            int ba = ((nt * 16 + nn) * 256 + ks * 64 + g * 16) ^ ((nn & 7) << 4);
            short8 bhi = *(const short8*)(Wl + ba);
            short8 blo = *(const short8*)(Wl + 32768 + ba);
            acc[nt] = __builtin_amdgcn_mfma_f32_16x16x32_bf16(a, blo, acc[nt], 0, 0, 0);
            acc[nt] = __builtin_amdgcn_mfma_f32_16x16x32_bf16(a, bhi, acc[nt], 0, 0, 0);
        }
    }

    __syncthreads();  // all waves done reading W -> Wl reusable

    // stage D tile into LDS: row stride 272B (16B-aligned, rotates banks by 4/row)
    // lane (nn,g) holds col nt*16+nn, rows (wv*16 + 4g + j)
    #pragma unroll
    for (int nt = 0; nt < 8; ++nt) {
        #pragma unroll
        for (int j = 0; j < 4; ++j) {
            int r = wv * 16 + 4 * g + j;
            *(unsigned short*)(Wl + r * 272 + (nt * 16 + nn) * 2) = f2bf(acc[nt][j]);
        }
    }
    __syncthreads();

    // coalesced writeback: 2048 uint4 chunks (128 rows x 16 chunks), 4 per thread
    #pragma unroll
    for (int it = 0; it < 4; ++it) {
        int idx = it * 512 + tid;
        int r = idx >> 4, ch = idx & 15;
        int gr = blockIdx.x * 128 + r;
        if (gr < N) {
            uint4 v = *(const uint4*)(Wl + r * 272 + ch * 16);
            *reinterpret_cast<uint4*>(&Hb[(size_t)gr * DD + ch * 8]) = v;
        }
    }
}

// ---------------- aggregation ----------------
// OUT[n] = dinv[n] * sum_e dinv[col[e]]*Hb[col[e]] + 2*dinv[n]^2*Hb[n] + b + F[n] (+X[n])
// one wave per node; lane handles 2 channels; 16-deep gather batches for MLP.

__global__ __launch_bounds__(256) void k_agg(const unsigned short* __restrict__ Hb,
                                             const int* __restrict__ rowp,
                                             const int* __restrict__ col,
                                             const float* __restrict__ dinv,
                                             const float* __restrict__ bias,
                                             const float* __restrict__ F,
                                             const float* __restrict__ X,
                                             float* __restrict__ OUT, int N, int addX) {
    int lane = threadIdx.x & 63;
    int n = (blockIdx.x << 2) + (threadIdx.x >> 6);
    if (n >= N) return;
    int c = lane << 1;
    size_t base = (size_t)n * DD + c;

    float di = dinv[n];
    unsigned hv = *reinterpret_cast<const unsigned*>(&Hb[base]);
    float s2 = 2.f * di * di;
    float sx = s2 * bf2f((unsigned short)(hv & 0xffff));
    float sy = s2 * bf2f((unsigned short)(hv >> 16));
    float ax = 0.f, ay = 0.f;  // edge accumulation (di applied at end)

    int e = rowp[n], e1 = rowp[n + 1];
    for (; e + 16 <= e1; e += 16) {
        int s[16];
        float w[16];
        unsigned gg[16];
        #pragma unroll
        for (int j = 0; j < 16; ++j) s[j] = col[e + j];
        #pragma unroll
        for (int j = 0; j < 16; ++j) w[j] = dinv[s[j]];
        #pragma unroll
        for (int j = 0; j < 16; ++j)
            gg[j] = *reinterpret_cast<const unsigned*>(&Hb[(size_t)s[j] * DD + c]);
        #pragma unroll
        for (int j = 0; j < 16; ++j) {
            ax += w[j] * bf2f((unsigned short)(gg[j] & 0xffff));
            ay += w[j] * bf2f((unsigned short)(gg[j] >> 16));
        }
    }
    for (; e + 4 <= e1; e += 4) {
        int s[4];
        float w[4];
        unsigned gg[4];
        #pragma unroll
        for (int j = 0; j < 4; ++j) s[j] = col[e + j];
        #pragma unroll
        for (int j = 0; j < 4; ++j) w[j] = dinv[s[j]];
        #pragma unroll
        for (int j = 0; j < 4; ++j)
            gg[j] = *reinterpret_cast<const unsigned*>(&Hb[(size_t)s[j] * DD + c]);
        #pragma unroll
        for (int j = 0; j < 4; ++j) {
            ax += w[j] * bf2f((unsigned short)(gg[j] & 0xffff));
            ay += w[j] * bf2f((unsigned short)(gg[j] >> 16));
        }
    }
    for (; e < e1; ++e) {
        int s0 = col[e];
        float w0 = dinv[s0];
        unsigned g0 = *reinterpret_cast<const unsigned*>(&Hb[(size_t)s0 * DD + c]);
        ax += w0 * bf2f((unsigned short)(g0 & 0xffff));
        ay += w0 * bf2f((unsigned short)(g0 >> 16));
    }

    float2 bv = *reinterpret_cast<const float2*>(&bias[c]);
    float2 fv = *reinterpret_cast<const float2*>(&F[base]);
    float ox = di * ax + sx + bv.x + fv.x;
    float oy = di * ay + sy + bv.y + fv.y;
    if (addX) {
        float2 xv = *reinterpret_cast<const float2*>(&X[base]);
        ox += xv.x;
        oy += xv.y;
    }
    float2 o;
    o.x = ox;
    o.y = oy;
    *reinterpret_cast<float2*>(&OUT[base]) = o;
}

// ---------------- launch ----------------

extern "C" void kernel_launch(void* const* d_in, const int* in_sizes, int n_in,
                              void* d_out, int out_size, void* d_ws, size_t ws_size,
                              hipStream_t stream) {
    const float* x  = (const float*)d_in[0];
    const int*   ei = (const int*)d_in[1];
    const float* W0 = (const float*)d_in[2];
    const float* b0 = (const float*)d_in[3];
    const float* W1 = (const float*)d_in[4];
    const float* b1 = (const float*)d_in[5];
    const float* W2 = (const float*)d_in[6];
    const float* b2 = (const float*)d_in[7];
    float* out = (float*)d_out;

    const int N = NN, E = NE;
    const int* srcA = ei;       // edge_index[0]
    const int* dstA = ei + E;   // edge_index[1]

    char* ws = (char*)d_ws;
    size_t off = 0;
    auto alloc = [&](size_t bytes) -> char* {
        char* p = ws + off;
        off += (bytes + 255) & ~size_t(255);
        return p;
    };
    int*   rowp   = (int*)  alloc((size_t)(N + 1) * sizeof(int));
    int*   bcur   = (int*)  alloc(1024 * sizeof(int));
    int*   bsum   = (int*)  alloc(512 * sizeof(int));
    float* dinv   = (float*)alloc((size_t)N * sizeof(float));
    int*   col    = (int*)  alloc((size_t)E * sizeof(int));
    uint2* tmp    = (uint2*)alloc((size_t)E * sizeof(uint2));
    unsigned short* h   = (unsigned short*)alloc((size_t)N * DD * sizeof(unsigned short));
    unsigned short* wt0 = (unsigned short*)alloc(65536);
    unsigned short* wt1 = (unsigned short*)alloc(65536);
    unsigned short* wt2 = (unsigned short*)alloc(65536);
    (void)ws_size; (void)in_sizes; (void)n_in; (void)out_size;

    hipMemsetAsync(rowp, 0, (size_t)(N + 1) * sizeof(int), stream);

    int gE = (E + 255) / 256;     // 6250
    int gN = (N + 255) / 256;     // 391
    int NB = (N + 127) / 128;     // 782 buckets
    k_count<<<gE, 256, 0, stream>>>(dstA, rowp + 1, E);
    k_prep <<<64, 256, 0, stream>>>(W0, wt0);
    k_prep <<<64, 256, 0, stream>>>(W1, wt1);
    k_prep <<<64, 256, 0, stream>>>(W2, wt2);
    k_dinv <<<gN, 256, 0, stream>>>(rowp, dinv, N);
    k_scan1<<<gN, 256, 0, stream>>>(rowp, bsum, N);
    k_scan2<<<1, 512, 0, stream>>>(bsum, gN);
    k_scan3<<<gN, 256, 0, stream>>>(rowp, bsum, bcur, N);
    k_part <<<256, 256, 0, stream>>>(srcA, dstA, bcur, tmp, E, NB);
    k_place<<<NB, 256, 0, stream>>>(tmp, rowp, col, N);

    int gG = (N + 127) / 128;  // 782
    int gA = (N + 3) / 4;      // 25000

    // layer 0: F = x -> out
    k_gemm<<<gG, 512, 0, stream>>>(x, wt0, h, N);
    k_agg <<<gA, 256, 0, stream>>>(h, rowp, col, dinv, b0, x, nullptr, out, N, 0);
    // layer 1: F = out -> out (in-place safe: each row read only by its own wave)
    k_gemm<<<gG, 512, 0, stream>>>(out, wt1, h, N);
    k_agg <<<gA, 256, 0, stream>>>(h, rowp, col, dinv, b1, out, nullptr, out, N, 0);
    // layer 2: F = out -> out, plus global residual x
    k_gemm<<<gG, 512, 0, stream>>>(out, wt2, h, N);
    k_agg <<<gA, 256, 0, stream>>>(h, rowp, col, dinv, b2, out, x, out, N, 1);
}